// Round 16
// baseline (78.277 us; speedup 1.0000x reference)
//
#include <hip/hip_runtime.h>

// Chamfer loss: x [B,N,D], y [B,M,D], D=3, fp32.
// dist[b,m,n] = ||x[b,n]-y[b,m]||^2
// row[b] = mean_n min_m dist ; col[b] = mean_m min_n dist
// out = mean_b max(row, col)
//
// R16: R15 structure with the hot loop rebuilt on inline-asm packed fp32
// (v_pk_fma_f32 / v_pk_add_f32, VOP3P). Packed across QUERY PAIRS; the
// wave-uniform target components broadcast via op_sel from the float4's
// natural register pairs (axy, azw) — zero splat cost. Per 2 targets x
// 2 queries: 8 pk + 4 v_min3 = 3.0 instr-slots/pair (scalar floor was 5.0).
// This settles R8's ambiguity: full-rate pk -> ~-5 us; half-rate pk -> flat
// and the scalar form was already at the CDNA4 fp32 issue ceiling.

#define BATCH   32
#define NPTS    2048
#define THREADS 128
#define QPT     16             // 128*16 = 2048 x-queries per block
#define QP      (QPT / 2)      // 8 query pairs
#define TCH     32             // y-chunks per batch
#define TC      (NPTS / TCH)   // 64 y-targets per chunk
#define GRP     32             // targets per col-reduce group
#define NGRP    (TC / GRP)     // 2 groups
#define NROWB   (BATCH * 8)    // 256 row-combine blocks
#define NCOLB   BATCH          // 32 col-sum blocks

typedef float v2f __attribute__((ext_vector_type(2)));

__global__ __launch_bounds__(THREADS, 1) void chamfer_min(
    const float* __restrict__ x, const float* __restrict__ y,
    float* __restrict__ part    /* [BATCH][TCH][NPTS] */,
    float* __restrict__ colmin  /* [BATCH][NPTS] */)
{
    __shared__ __align__(16) float4 t4[TC];    // 64 targets — 1 KB
    __shared__ float colLds[THREADS][GRP + 1]; // 16.9 KB, stride 33
    __shared__ float cmPart[4][GRP + 1];       // 528 B

    const int blk   = blockIdx.x;      // 1024
    const int b     = blk >> 5;
    const int chunk = blk & 31;

    const float* qp = x + (size_t)b * NPTS * 3;
    const float* tp = y + (size_t)b * NPTS * 3;

    // Stage this chunk's 64 y-targets with h_y = 0.5*||y||^2.
    if (threadIdx.x < TC) {
        int jj = chunk * TC + threadIdx.x;
        float ty0 = tp[3 * jj + 0];
        float ty1 = tp[3 * jj + 1];
        float ty2 = tp[3 * jj + 2];
        t4[threadIdx.x] = make_float4(ty0, ty1, ty2,
                                      0.5f * (ty0 * ty0 + ty1 * ty1 + ty2 * ty2));
    }

    // 16 x-queries per thread as 8 packed pairs: {-q(2p), -q(2p+1)} etc.
    v2f nqxp[QP], nqyp[QP], nqzp[QP], hxp[QP];
    float mn[QPT];
#pragma unroll
    for (int p = 0; p < QP; ++p) {
        int qi0 = threadIdx.x + (2 * p) * THREADS;
        int qi1 = threadIdx.x + (2 * p + 1) * THREADS;
        float ax = qp[3 * qi0 + 0], ay = qp[3 * qi0 + 1], az = qp[3 * qi0 + 2];
        float bx = qp[3 * qi1 + 0], by = qp[3 * qi1 + 1], bz = qp[3 * qi1 + 2];
        nqxp[p] = (v2f){-ax, -bx};
        nqyp[p] = (v2f){-ay, -by};
        nqzp[p] = (v2f){-az, -bz};
        hxp[p]  = (v2f){0.5f * (ax * ax + ay * ay + az * az),
                        0.5f * (bx * bx + by * by + bz * bz)};
        mn[2 * p] = 3.4e38f;
        mn[2 * p + 1] = 3.4e38f;
    }
    __syncthreads();

    // 2 groups of 32 targets: packed hot scan + col tree-reduce per group.
#pragma unroll 1
    for (int g = 0; g < NGRP; ++g) {
        const float4* tg = &t4[g * GRP];
#pragma unroll 2
        for (int j = 0; j < GRP; j += 2) {
            // Target components as natural register pairs for op_sel bcast.
            v2f axy = *(const v2f*)&tg[j].x;       // {a.x, a.y}
            v2f azw = *(const v2f*)&tg[j].z;       // {a.z, h_a}
            v2f cxy = *(const v2f*)&tg[j + 1].x;   // {c.x, c.y}
            v2f czw = *(const v2f*)&tg[j + 1].z;   // {c.z, h_c}
            float colA = 3.4e38f, colC = 3.4e38f;
#pragma unroll
            for (int p = 0; p < QP; ++p) {
                v2f Wa, u1a, u2a, sA, Wc, u1c, u2c, sC;
                // W = h_t (bcast hi of azw) + hx pair
                asm("v_pk_add_f32 %0, %1, %2 op_sel:[1,0] op_sel_hi:[1,1]"
                    : "=v"(Wa) : "v"(azw), "v"(hxp[p]));
                asm("v_pk_add_f32 %0, %1, %2 op_sel:[1,0] op_sel_hi:[1,1]"
                    : "=v"(Wc) : "v"(czw), "v"(hxp[p]));
                // u1 = a.x (bcast lo) * nqx + W
                asm("v_pk_fma_f32 %0, %1, %2, %3 op_sel:[0,0,0] op_sel_hi:[0,1,1]"
                    : "=v"(u1a) : "v"(axy), "v"(nqxp[p]), "v"(Wa));
                asm("v_pk_fma_f32 %0, %1, %2, %3 op_sel:[0,0,0] op_sel_hi:[0,1,1]"
                    : "=v"(u1c) : "v"(cxy), "v"(nqxp[p]), "v"(Wc));
                // u2 = a.y (bcast hi) * nqy + u1
                asm("v_pk_fma_f32 %0, %1, %2, %3 op_sel:[1,0,0] op_sel_hi:[1,1,1]"
                    : "=v"(u2a) : "v"(axy), "v"(nqyp[p]), "v"(u1a));
                asm("v_pk_fma_f32 %0, %1, %2, %3 op_sel:[1,0,0] op_sel_hi:[1,1,1]"
                    : "=v"(u2c) : "v"(cxy), "v"(nqyp[p]), "v"(u1c));
                // s = a.z (bcast lo) * nqz + u2
                asm("v_pk_fma_f32 %0, %1, %2, %3 op_sel:[0,0,0] op_sel_hi:[0,1,1]"
                    : "=v"(sA) : "v"(azw), "v"(nqzp[p]), "v"(u2a));
                asm("v_pk_fma_f32 %0, %1, %2, %3 op_sel:[0,0,0] op_sel_hi:[0,1,1]"
                    : "=v"(sC) : "v"(czw), "v"(nqzp[p]), "v"(u2c));
                // Row mins (per query, across the 2 targets): v_min3
                mn[2 * p]     = fminf(fminf(mn[2 * p],     sA.x), sC.x);
                mn[2 * p + 1] = fminf(fminf(mn[2 * p + 1], sA.y), sC.y);
                // Col mins (per target, across the 2 queries): v_min3
                colA = fminf(fminf(colA, sA.x), sA.y);
                colC = fminf(fminf(colC, sC.x), sC.y);
            }
            colLds[threadIdx.x][j]     = colA;
            colLds[threadIdx.x][j + 1] = colC;
        }
        __syncthreads();

        // Col tree: 4 row-groups of 32 threads, one (rowgroup, target)/thread.
        {
            const int rg = threadIdx.x >> 5;   // 0..3
            const int t  = threadIdx.x & 31;   // target within group
            float cp = 3.4e38f;
#pragma unroll
            for (int i = 0; i < 32; ++i)
                cp = fminf(cp, colLds[rg * 32 + i][t]);
            cmPart[rg][t] = cp;
        }
        __syncthreads();
        if (threadIdx.x < GRP) {
            const int t = threadIdx.x;
            float cm = fminf(fminf(cmPart[0][t], cmPart[1][t]),
                             fminf(cmPart[2][t], cmPart[3][t]));
            colmin[(size_t)b * NPTS + chunk * TC + g * GRP + t] = cm;
        }
        __syncthreads();
    }

    // Row partials: plain coalesced writes — no init, no atomics.
    float* pbase = part + ((size_t)b * TCH + chunk) * NPTS;
#pragma unroll
    for (int k = 0; k < QPT; ++k)
        pbase[threadIdx.x + k * THREADS] = mn[k];
}

#define CTHREADS 256

__global__ __launch_bounds__(CTHREADS) void chamfer_combine(
    const float* __restrict__ part,
    const float* __restrict__ colmin,
    float* __restrict__ blocksums /* [NROWB + NCOLB] */)
{
    __shared__ float wsum[CTHREADS / 64];

    const int blk = blockIdx.x;        // 288 = NROWB + NCOLB
    float d;

    if (blk < NROWB) {
        // Row: min over 32 chunks for one query, d = 2c.
        const int b  = blk >> 3;
        const int qc = blk & 7;
        const int qi = qc * CTHREADS + threadIdx.x;
        const float* p = part + (size_t)b * TCH * NPTS + qi;
        float mn = p[0];
#pragma unroll
        for (int c = 1; c < TCH; ++c)
            mn = fminf(mn, p[(size_t)c * NPTS]);
        d = 2.0f * mn;
    } else {
        // Col: sum 2*colmin over this batch (8 values per thread).
        const int b = blk - NROWB;
        const float* p = colmin + (size_t)b * NPTS;
        float s = 0.0f;
#pragma unroll
        for (int i = 0; i < 8; ++i)
            s += p[threadIdx.x + i * CTHREADS];
        d = 2.0f * s;
    }

    for (int off = 32; off > 0; off >>= 1)
        d += __shfl_down(d, off);
    if ((threadIdx.x & 63) == 0) wsum[threadIdx.x >> 6] = d;
    __syncthreads();
    if (threadIdx.x == 0)
        blocksums[blk] = wsum[0] + wsum[1] + wsum[2] + wsum[3];
}

__global__ void chamfer_finalize(const float* __restrict__ blocksums,
                                 float* __restrict__ out)
{
    const int lane = threadIdx.x;   // 64 threads; lanes >= 32 contribute 0
    float v = 0.0f;
    if (lane < BATCH) {
        float rs = 0.0f;
#pragma unroll
        for (int i = 0; i < 8; ++i)
            rs += blocksums[lane * 8 + i];
        float cs = blocksums[NROWB + lane];
        v = fmaxf(rs, cs) * (1.0f / NPTS);
    }
    for (int off = 32; off > 0; off >>= 1)
        v += __shfl_down(v, off);
    if (lane == 0) out[0] = v * (1.0f / BATCH);
}

extern "C" void kernel_launch(void* const* d_in, const int* in_sizes, int n_in,
                              void* d_out, int out_size, void* d_ws, size_t ws_size,
                              hipStream_t stream) {
    const float* x = (const float*)d_in[0];
    const float* y = (const float*)d_in[1];
    float* out = (float*)d_out;

    float* part      = (float*)d_ws;                          // 8 MB
    float* colmin    = part + (size_t)BATCH * TCH * NPTS;     // 256 KB
    float* blocksums = colmin + (size_t)BATCH * NPTS;         // ~1.2 KB

    chamfer_min<<<BATCH * TCH, THREADS, 0, stream>>>(x, y, part, colmin);
    chamfer_combine<<<NROWB + NCOLB, CTHREADS, 0, stream>>>(part, colmin, blocksums);
    chamfer_finalize<<<1, 64, 0, stream>>>(blocksums, out);
}